// Round 14
// baseline (241.878 us; speedup 1.0000x reference)
//
#include <hip/hip_runtime.h>

#define IN_C 128
#define HID_C 128
#define OUT_C 64
#define BN_EPS 1e-5f
#define BUCK_SHIFT 8            // 256 nodes per bucket
#define MAXBUCK 512             // supports n up to 131071 (17-bit row id in pack)
#define CHUNK_SHIFT 13          // 8192-node source chunks
#define NSB 256                 // hist/scatter blocks (256 -> full parallelism)

typedef unsigned short ushort_t;
typedef __attribute__((ext_vector_type(8))) short bf16x8;
typedef __attribute__((ext_vector_type(4))) float f32x4;
typedef __attribute__((ext_vector_type(8))) unsigned short u16x8;

__device__ __forceinline__ float bf2f(ushort_t u) {
  union { unsigned i; float f; } c; c.i = (unsigned)u << 16; return c.f;
}
__device__ __forceinline__ ushort_t f2bf(float f) {
  union { float f; unsigned u; } c; c.f = f;
  unsigned r = c.u + 0x7FFF + ((c.u >> 16) & 1);
  return (ushort_t)(r >> 16);
}

// ---------------- CSR build via bucket counting sort (no global atomics) ----

__global__ __launch_bounds__(256) void k_hist(const int* __restrict__ col,
                                              int* __restrict__ ghist,
                                              int e, int nbuck, int chunk) {
  __shared__ int h[MAXBUCK];
  for (int p = threadIdx.x; p < nbuck; p += 256) h[p] = 0;
  __syncthreads();
  int s = blockIdx.x * chunk;
  int t = min(s + chunk, e);
  for (int i = s + threadIdx.x; i < t; i += 256)
    atomicAdd(&h[col[i] >> BUCK_SHIFT], 1);
  __syncthreads();
  for (int p = threadIdx.x; p < nbuck; p += 256)
    ghist[p * NSB + blockIdx.x] = h[p];
}

__global__ __launch_bounds__(256) void k_s1(int* __restrict__ ghist,
                                            int* __restrict__ btotal, int nbuck) {
  __shared__ int sd[256];
  int p = blockIdx.x;
  int tid = threadIdx.x;
  int idx = p * NSB + tid;
  int v = ghist[idx];
  sd[tid] = v;
  __syncthreads();
  for (int off = 1; off < 256; off <<= 1) {
    int t = (tid >= off) ? sd[tid - off] : 0;
    __syncthreads();
    sd[tid] += t;
    __syncthreads();
  }
  ghist[idx] = sd[tid] - v;    // exclusive within bucket
  if (tid == 255) btotal[p] = sd[255];
}

__global__ __launch_bounds__(512) void k_s2(const int* __restrict__ btotal,
                                            int* __restrict__ bstart,
                                            int nbuck, int e,
                                            int* __restrict__ rowptr, int n) {
  __shared__ int sd[512];
  int tid = threadIdx.x;
  int v = (tid < nbuck) ? btotal[tid] : 0;
  sd[tid] = v;
  __syncthreads();
  for (int off = 1; off < 512; off <<= 1) {
    int t = (tid >= off) ? sd[tid - off] : 0;
    __syncthreads();
    sd[tid] += t;
    __syncthreads();
  }
  if (tid < nbuck) bstart[tid] = sd[tid] - v;
  if (tid == 0) { bstart[nbuck] = e; rowptr[n] = e; }
}

__global__ __launch_bounds__(256) void k_scatter(const int* __restrict__ row,
                                                 const int* __restrict__ col,
                                                 const int* __restrict__ ghist,
                                                 const int* __restrict__ bstart,
                                                 unsigned* __restrict__ bpack,
                                                 int e, int nbuck, int chunk) {
  __shared__ int cur[MAXBUCK];
  for (int p = threadIdx.x; p < nbuck; p += 256)
    cur[p] = bstart[p] + ghist[p * NSB + blockIdx.x];
  __syncthreads();
  int s = blockIdx.x * chunk;
  int t = min(s + chunk, e);
  for (int i = s + threadIdx.x; i < t; i += 256) {
    int c = col[i];
    int pos = atomicAdd(&cur[c >> BUCK_SHIFT], 1);
    bpack[pos] = ((unsigned)(c & 255) << 17) | (unsigned)row[i];
  }
}

__global__ __launch_bounds__(256) void k_bsort(const unsigned* __restrict__ bpack,
                                               const int* __restrict__ bstart,
                                               int* __restrict__ rowptr,
                                               float* __restrict__ dis,
                                               int* __restrict__ srcidx, int n) {
  __shared__ int cnt[4096];
  __shared__ int excl[4097];
  __shared__ int sd[256];
  __shared__ int sbs, sbe;
  int tid = threadIdx.x;
  int p = blockIdx.x;
  for (int q = tid; q < 4096; q += 256) cnt[q] = 0;
  if (tid == 0) { sbs = bstart[p]; sbe = bstart[p + 1]; }
  __syncthreads();
  int bs = sbs, be = sbe;
  for (int i = bs + tid; i < be; i += 256) {
    unsigned v = bpack[i];
    int key = (int)((v >> 17) << 4) | (int)((v & 0x1FFFFu) >> CHUNK_SHIFT);
    atomicAdd(&cnt[key], 1);
  }
  __syncthreads();
  int base = tid * 16;
  int c[16]; int s = 0;
#pragma unroll
  for (int q = 0; q < 16; q++) { c[q] = cnt[base + q]; s += c[q]; }
  sd[tid] = s;
  __syncthreads();
  for (int off = 1; off < 256; off <<= 1) {
    int t = (tid >= off) ? sd[tid - off] : 0;
    __syncthreads();
    sd[tid] += t;
    __syncthreads();
  }
  int run = sd[tid] - s;
  int st = run;
#pragma unroll
  for (int q = 0; q < 16; q++) { excl[base + q] = run; run += c[q]; }
  if (tid == 255) excl[4096] = sd[255];
  int node = (p << BUCK_SHIFT) + tid;
  if (node < n) {
    rowptr[node] = bs + st;
    dis[node] = rsqrtf((float)(s + 1));  // +1 self loop
  }
  __syncthreads();
  for (int i = bs + tid; i < be; i += 256) {
    unsigned v = bpack[i];
    int key = (int)((v >> 17) << 4) | (int)((v & 0x1FFFFu) >> CHUNK_SHIFT);
    int q = atomicAdd(&excl[key], 1);
    srcidx[bs + q] = (int)(v & 0x1FFFFu);
  }
}

// ------- weight pack: WB[n][k] = W[k][n] in bf16; also zero stats -------

__global__ void k_wpack(const float* __restrict__ W1, const float* __restrict__ W2,
                        ushort_t* __restrict__ WB1, ushort_t* __restrict__ WB2,
                        float* __restrict__ stats) {
  int idx = blockIdx.x * 256 + threadIdx.x;
  if (blockIdx.x == 0) stats[threadIdx.x] = 0.f;
  if (idx < 128 * 128) {
    int nn = idx >> 7, k = idx & 127;
    WB1[idx] = f2bf(W1[k * HID_C + nn]);
  }
  int idx2 = idx - 128 * 128;
  if (idx2 >= 0 && idx2 < 64 * 128) {
    int nn = idx2 >> 7, k = idx2 & 127;
    WB2[idx2] = f2bf(W2[k * OUT_C + nn]);
  }
}

// ------- GEMM1 (MFMA bf16): h1p = bf16(dis*(x@W1)) -------
// LDS-staged coalesced x loads + LDS-transposed coalesced u16x8 stores.

__global__ __launch_bounds__(256) void k_gemm1_mfma(const float* __restrict__ x,
                                                    const ushort_t* __restrict__ WB,
                                                    const float* __restrict__ dis,
                                                    ushort_t* __restrict__ h1, int n) {
  __shared__ float xs[64][132];
  int tid = threadIdx.x;
  int base = blockIdx.x * 64;
#pragma unroll
  for (int k = 0; k < 8; k++) {
    int idx = tid + k * 256;          // 0..2047
    int r = idx >> 5;                 // row 0..63
    int c4 = (idx & 31) << 2;         // float col, step 4
    int rowi = base + r;
    float4 v;
    if (rowi < n) v = *reinterpret_cast<const float4*>(&x[(size_t)rowi * IN_C + c4]);
    else { v.x = 0.f; v.y = 0.f; v.z = 0.f; v.w = 0.f; }
    *reinterpret_cast<float4*>(&xs[r][c4]) = v;
  }
  __syncthreads();
  int wave = tid >> 6;
  int lane = tid & 63;
  int m = lane & 15;
  int kg = lane >> 4;
  int rowbase = base + wave * 16;
  f32x4 acc[8] = {};
#pragma unroll
  for (int ks = 0; ks < 4; ks++) {
    const float* xr = &xs[wave * 16 + m][ks * 32 + kg * 8];
    float4 a0 = *reinterpret_cast<const float4*>(xr);
    float4 a1 = *reinterpret_cast<const float4*>(xr + 4);
    bf16x8 a;
    a[0] = (short)f2bf(a0.x); a[1] = (short)f2bf(a0.y);
    a[2] = (short)f2bf(a0.z); a[3] = (short)f2bf(a0.w);
    a[4] = (short)f2bf(a1.x); a[5] = (short)f2bf(a1.y);
    a[6] = (short)f2bf(a1.z); a[7] = (short)f2bf(a1.w);
#pragma unroll
    for (int nt = 0; nt < 8; nt++) {
      bf16x8 b = *reinterpret_cast<const bf16x8*>(WB + (nt * 16 + m) * 128 + ks * 32 + kg * 8);
      acc[nt] = __builtin_amdgcn_mfma_f32_16x16x32_bf16(a, b, acc[nt], 0, 0, 0);
    }
  }
  // ---- epilogue: transpose through LDS (reuse xs), coalesced 16B stores ----
  ushort_t* hs = reinterpret_cast<ushort_t*>(&xs[0][0]);  // [64][136] ushort
  float dr_[4];
#pragma unroll
  for (int r = 0; r < 4; r++) {
    int rowi = rowbase + kg * 4 + r;
    dr_[r] = dis[rowi < n ? rowi : (n - 1)];
  }
  __syncthreads();                     // all xs reads done before overwrite
#pragma unroll
  for (int nt = 0; nt < 8; nt++)
#pragma unroll
    for (int r = 0; r < 4; r++)
      hs[(size_t)(wave * 16 + kg * 4 + r) * 136 + nt * 16 + m] = f2bf(dr_[r] * acc[nt][r]);
  __syncthreads();
#pragma unroll
  for (int k = 0; k < 4; k++) {
    int idx = tid + k * 256;           // 0..1023
    int r = idx >> 4;                  // row 0..63
    int c8 = (idx & 15) * 8;           // col 0..120
    int rowi = base + r;
    if (rowi < n)
      *reinterpret_cast<u16x8*>(&h1[(size_t)rowi * HID_C + c8]) =
          *reinterpret_cast<const u16x8*>(&hs[(size_t)r * 136 + c8]);
  }
}

// ------- GEMM2 (MFMA bf16, BN+ReLU fused; LDS-transposed coalesced stores) -------

__global__ __launch_bounds__(256) void k_gemm2_mfma(const ushort_t* __restrict__ aggb,
                                                    const ushort_t* __restrict__ WB,
                                                    const float* __restrict__ stats,
                                                    const float* __restrict__ gamma,
                                                    const float* __restrict__ beta,
                                                    const float* __restrict__ dis,
                                                    ushort_t* __restrict__ h2, int n) {
  __shared__ float bnp_s[256];
  __shared__ ushort_t hs2[64][72];
  int tid = threadIdx.x;
  if (tid < 128) {
    float inv_n = 1.f / (float)n;
    float mean = stats[tid] * inv_n;
    float var = stats[128 + tid] * inv_n - mean * mean;
    float istd = rsqrtf(var + BN_EPS);
    float sc = gamma[tid] * istd;
    bnp_s[tid] = sc;
    bnp_s[128 + tid] = beta[tid] - mean * sc;
  }
  __syncthreads();
  int wave = tid >> 6;
  int lane = tid & 63;
  int m = lane & 15;
  int kg = lane >> 4;
  int rowbase = blockIdx.x * 64 + wave * 16;
  int rrow = rowbase + m; if (rrow >= n) rrow = n - 1;
  const ushort_t* arow = aggb + (size_t)rrow * HID_C + kg * 8;
  f32x4 acc[4] = {};
#pragma unroll
  for (int ks = 0; ks < 4; ks++) {
    int kbase = ks * 32 + kg * 8;
    u16x8 av = *reinterpret_cast<const u16x8*>(arow + ks * 32);
    float v[8];
#pragma unroll
    for (int q = 0; q < 8; q++)
      v[q] = bf2f(av[q]) * bnp_s[kbase + q] + bnp_s[128 + kbase + q];
    bf16x8 a;
#pragma unroll
    for (int q = 0; q < 8; q++) a[q] = (short)f2bf(v[q] > 0.f ? v[q] : 0.f);
#pragma unroll
    for (int nt = 0; nt < 4; nt++) {
      bf16x8 b = *reinterpret_cast<const bf16x8*>(WB + (nt * 16 + m) * 128 + ks * 32 + kg * 8);
      acc[nt] = __builtin_amdgcn_mfma_f32_16x16x32_bf16(a, b, acc[nt], 0, 0, 0);
    }
  }
  // ---- epilogue: transpose through LDS, coalesced 16B stores ----
  float dr_[4];
#pragma unroll
  for (int r = 0; r < 4; r++) {
    int rowi = rowbase + kg * 4 + r;
    dr_[r] = dis[rowi < n ? rowi : (n - 1)];
  }
#pragma unroll
  for (int nt = 0; nt < 4; nt++)
#pragma unroll
    for (int r = 0; r < 4; r++)
      hs2[wave * 16 + kg * 4 + r][nt * 16 + m] = f2bf(dr_[r] * acc[nt][r]);
  __syncthreads();
#pragma unroll
  for (int k = 0; k < 2; k++) {
    int idx = tid + k * 256;           // 0..511
    int r = idx >> 3;                  // row 0..63
    int c8 = (idx & 7) * 8;            // col 0..56
    int rowi = blockIdx.x * 64 + r;
    if (rowi < n)
      *reinterpret_cast<u16x8*>(&h2[(size_t)rowi * OUT_C + c8]) =
          *reinterpret_cast<const u16x8*>(&hs2[r][c8]);
  }
}

// ------- SpMM1: XCD-parity channel halves (g = blockIdx&1 -> 64ch, 128B rows) -------
// XCDs 0,2,4,6 gather channels 0..63; 1,3,5,7 gather 64..127 -> per-XCD
// compulsory fill halves (12.8MB table slice per XCD instead of 25.6MB).

__global__ __launch_bounds__(256) void k_spmm1_bf(const ushort_t* __restrict__ h,
                                                  const float* __restrict__ dis,
                                                  const int* __restrict__ rowptr,
                                                  const int* __restrict__ srcidx,
                                                  const float* __restrict__ bias,
                                                  ushort_t* __restrict__ outp, int n) {
  constexpr int C = HID_C;         // table stride
  int tid = threadIdx.x;
  int g = blockIdx.x & 1;          // channel half (XCD parity)
  int lane = tid & 7;              // 8 lanes x 8ch = 64 channels
  int r = tid >> 3;                // 32 rows per block
  int i = (blockIdx.x >> 1) * 32 + r;
  if (i >= n) return;
  int c8 = g * 64 + lane * 8;
  const ushort_t* hb = h + c8;

  float acc[8];
  u16x8 hv = *reinterpret_cast<const u16x8*>(hb + (size_t)i * C);
#pragma unroll
  for (int q = 0; q < 8; q++) acc[q] = bf2f(hv[q]);   // self loop (premult)

  int s = rowptr[i], t = rowptr[i + 1];
  int p = s;
  for (; p + 16 <= t; p += 16) {
    int j[16]; u16x8 v[16];
#pragma unroll
    for (int k = 0; k < 16; k++) j[k] = srcidx[p + k];
#pragma unroll
    for (int k = 0; k < 16; k++)
      v[k] = *reinterpret_cast<const u16x8*>(hb + (size_t)j[k] * C);
#pragma unroll
    for (int k = 0; k < 16; k++)
#pragma unroll
      for (int q = 0; q < 8; q++) acc[q] += bf2f(v[k][q]);
  }
  for (; p + 4 <= t; p += 4) {
    int j[4]; u16x8 v[4];
#pragma unroll
    for (int k = 0; k < 4; k++) j[k] = srcidx[p + k];
#pragma unroll
    for (int k = 0; k < 4; k++)
      v[k] = *reinterpret_cast<const u16x8*>(hb + (size_t)j[k] * C);
#pragma unroll
    for (int k = 0; k < 4; k++)
#pragma unroll
      for (int q = 0; q < 8; q++) acc[q] += bf2f(v[k][q]);
  }
  for (; p < t; p++) {
    int j = srcidx[p];
    u16x8 v = *reinterpret_cast<const u16x8*>(hb + (size_t)j * C);
#pragma unroll
    for (int q = 0; q < 8; q++) acc[q] += bf2f(v[q]);
  }

  float di = dis[i];
  float4 b0 = *reinterpret_cast<const float4*>(bias + c8);
  float4 b1v = *reinterpret_cast<const float4*>(bias + c8 + 4);
  u16x8 o;
  o[0] = f2bf(di * acc[0] + b0.x);  o[1] = f2bf(di * acc[1] + b0.y);
  o[2] = f2bf(di * acc[2] + b0.z);  o[3] = f2bf(di * acc[3] + b0.w);
  o[4] = f2bf(di * acc[4] + b1v.x); o[5] = f2bf(di * acc[5] + b1v.y);
  o[6] = f2bf(di * acc[6] + b1v.z); o[7] = f2bf(di * acc[7] + b1v.w);
  *reinterpret_cast<u16x8*>(outp + (size_t)i * C + c8) = o;
}

// ------- SpMM2: XCD-parity channel halves (32ch = 64B rows, 1 full line) -------

__global__ __launch_bounds__(256) void k_spmm2_bf(const ushort_t* __restrict__ h,
                                                  const float* __restrict__ dis,
                                                  const int* __restrict__ rowptr,
                                                  const int* __restrict__ srcidx,
                                                  const float* __restrict__ bias,
                                                  float* __restrict__ outp, int n) {
  constexpr int C = OUT_C;         // table stride
  int tid = threadIdx.x;
  int g = blockIdx.x & 1;          // channel half (XCD parity)
  int lane = tid & 3;              // 4 lanes x 8ch = 32 channels
  int r = tid >> 2;                // 64 rows per block
  int i = (blockIdx.x >> 1) * 64 + r;
  if (i >= n) return;
  int c8 = g * 32 + lane * 8;
  const ushort_t* hb = h + c8;

  float acc[8];
  u16x8 hv = *reinterpret_cast<const u16x8*>(hb + (size_t)i * C);
#pragma unroll
  for (int q = 0; q < 8; q++) acc[q] = bf2f(hv[q]);

  int s = rowptr[i], t = rowptr[i + 1];
  int p = s;
  for (; p + 16 <= t; p += 16) {
    int j[16]; u16x8 v[16];
#pragma unroll
    for (int k = 0; k < 16; k++) j[k] = srcidx[p + k];
#pragma unroll
    for (int k = 0; k < 16; k++)
      v[k] = *reinterpret_cast<const u16x8*>(hb + (size_t)j[k] * C);
#pragma unroll
    for (int k = 0; k < 16; k++)
#pragma unroll
      for (int q = 0; q < 8; q++) acc[q] += bf2f(v[k][q]);
  }
  for (; p + 4 <= t; p += 4) {
    int j[4]; u16x8 v[4];
#pragma unroll
    for (int k = 0; k < 4; k++) j[k] = srcidx[p + k];
#pragma unroll
    for (int k = 0; k < 4; k++)
      v[k] = *reinterpret_cast<const u16x8*>(hb + (size_t)j[k] * C);
#pragma unroll
    for (int k = 0; k < 4; k++)
#pragma unroll
      for (int q = 0; q < 8; q++) acc[q] += bf2f(v[k][q]);
  }
  for (; p < t; p++) {
    int j = srcidx[p];
    u16x8 v = *reinterpret_cast<const u16x8*>(hb + (size_t)j * C);
#pragma unroll
    for (int q = 0; q < 8; q++) acc[q] += bf2f(v[q]);
  }

  float di = dis[i];
  float4 b0 = *reinterpret_cast<const float4*>(bias + c8);
  float4 b1v = *reinterpret_cast<const float4*>(bias + c8 + 4);
  float4 o0, o1;
  o0.x = di * acc[0] + b0.x;  o0.y = di * acc[1] + b0.y;
  o0.z = di * acc[2] + b0.z;  o0.w = di * acc[3] + b0.w;
  o1.x = di * acc[4] + b1v.x; o1.y = di * acc[5] + b1v.y;
  o1.z = di * acc[6] + b1v.z; o1.w = di * acc[7] + b1v.w;
  float* op = outp + (size_t)i * C + c8;
  *reinterpret_cast<float4*>(op) = o0;
  *reinterpret_cast<float4*>(op + 4) = o1;
}

// ---------------- BN stats over bf16 agg (vectorized) ----------------

__global__ __launch_bounds__(256) void k_bnstats(const ushort_t* __restrict__ aggb,
                                                 float* __restrict__ stats, int n) {
  __shared__ float lsum[256 * 8];
  __shared__ float lsq[256 * 8];
  int tid = threadIdx.x;
  int lane = tid & 15;          // channel-octet
  int rg = tid >> 4;            // row-in-group 0..15
  float s[8] = {}, q[8] = {};
  for (int row = blockIdx.x * 16 + rg; row < n; row += gridDim.x * 16) {
    u16x8 v = *reinterpret_cast<const u16x8*>(aggb + (size_t)row * HID_C + lane * 8);
#pragma unroll
    for (int k = 0; k < 8; k++) {
      float f = bf2f(v[k]);
      s[k] += f;
      q[k] += f * f;
    }
  }
#pragma unroll
  for (int k = 0; k < 8; k++) { lsum[tid * 8 + k] = s[k]; lsq[tid * 8 + k] = q[k]; }
  __syncthreads();
  if (tid < 128) {
    int ln = tid >> 3, k = tid & 7;   // channel c = ln*8+k
    float ss = 0.f, qq = 0.f;
    for (int r = 0; r < 16; r++) {
      int idx = ((r << 4) + ln) * 8 + k;
      ss += lsum[idx];
      qq += lsq[idx];
    }
    atomicAdd(&stats[tid], ss);
    atomicAdd(&stats[128 + tid], qq);
  }
}

// ---------------- launch ----------------

extern "C" void kernel_launch(void* const* d_in, const int* in_sizes, int n_in,
                              void* d_out, int out_size, void* d_ws, size_t ws_size,
                              hipStream_t stream) {
  const float* x     = (const float*)d_in[0];
  const int*   edge  = (const int*)d_in[1];
  const float* W1    = (const float*)d_in[2];
  const float* b1    = (const float*)d_in[3];
  const float* gamma = (const float*)d_in[4];
  const float* beta  = (const float*)d_in[5];
  const float* W2    = (const float*)d_in[6];
  const float* b2    = (const float*)d_in[7];
  float* out = (float*)d_out;

  int n = in_sizes[0] / IN_C;
  int e = in_sizes[1] / 2;
  int n64 = ((n + 63) / 64) * 64;
  int nbuck = (n + (1 << BUCK_SHIFT) - 1) >> BUCK_SHIFT;
  const int* row = edge;      // edge_index[0] = source j
  const int* col = edge + e;  // edge_index[1] = target i

  char* ws = (char*)d_ws;
  size_t off = 0;
  auto alloc = [&](size_t bytes) {
    void* p = ws + off;
    off = (off + bytes + 255) & ~(size_t)255;
    return p;
  };
  // persistent
  float*    dis   = (float*)alloc((size_t)n * 4);
  int*      rowp  = (int*)alloc((size_t)(n + 1) * 4);
  int*      srci  = (int*)alloc((size_t)e * 4);
  ushort_t* WB1   = (ushort_t*)alloc(128 * 128 * 2);
  ushort_t* WB2   = (ushort_t*)alloc(64 * 128 * 2);
  ushort_t* h1b   = (ushort_t*)alloc((size_t)n64 * HID_C * 2);
  ushort_t* aggb  = (ushort_t*)alloc((size_t)n64 * HID_C * 2);
  ushort_t* h2b   = (ushort_t*)alloc((size_t)n64 * OUT_C * 2);
  float*    stats = (float*)alloc(256 * 4);
  // transients overlay aggb (dead until spmm1 writes it, after bsort)
  char* tr = (char*)aggb;
  unsigned* bpack = (unsigned*)tr;                       tr += (size_t)e * 4;
  int* ghist  = (int*)tr;                                tr += (size_t)NSB * nbuck * 4;
  int* btotal = (int*)tr;                                tr += (size_t)(nbuck + 1) * 4;
  int* bstart = (int*)tr;
  (void)ws_size; (void)n_in; (void)out_size;

  int chunk = (e + NSB - 1) / NSB;
  int nb64 = n64 / 64;

  k_wpack  <<<96, 256, 0, stream>>>(W1, W2, WB1, WB2, stats);
  k_hist   <<<NSB, 256, 0, stream>>>(col, ghist, e, nbuck, chunk);
  k_s1     <<<nbuck, 256, 0, stream>>>(ghist, btotal, nbuck);
  k_s2     <<<1, 512, 0, stream>>>(btotal, bstart, nbuck, e, rowp, n);
  k_scatter<<<NSB, 256, 0, stream>>>(row, col, ghist, bstart, bpack, e, nbuck, chunk);
  k_bsort  <<<nbuck, 256, 0, stream>>>(bpack, bstart, rowp, dis, srci, n);
  k_gemm1_mfma<<<nb64, 256, 0, stream>>>(x, WB1, dis, h1b, n);
  k_spmm1_bf<<<2 * ((n + 31) / 32), 256, 0, stream>>>(h1b, dis, rowp, srci, b1, aggb, n);
  k_bnstats<<<512, 256, 0, stream>>>(aggb, stats, n);
  k_gemm2_mfma<<<nb64, 256, 0, stream>>>(aggb, WB2, stats, gamma, beta, dis, h2b, n);
  k_spmm2_bf<<<2 * ((n + 63) / 64), 256, 0, stream>>>(h2b, dis, rowp, srci, b2, out, n);
}

// Round 15
// 220.624 us; speedup vs baseline: 1.0963x; 1.0963x over previous
//
#include <hip/hip_runtime.h>

#define IN_C 128
#define HID_C 128
#define OUT_C 64
#define BN_EPS 1e-5f
#define BUCK_SHIFT 8            // 256 nodes per bucket
#define MAXBUCK 512             // supports n up to 131071 (17-bit row id in pack)
#define CHUNK_SHIFT 13          // 8192-node source chunks
#define NSB 256                 // hist/scatter blocks (256 -> full parallelism)

typedef unsigned short ushort_t;
typedef __attribute__((ext_vector_type(8))) short bf16x8;
typedef __attribute__((ext_vector_type(4))) float f32x4;
typedef __attribute__((ext_vector_type(8))) unsigned short u16x8;

__device__ __forceinline__ float bf2f(ushort_t u) {
  union { unsigned i; float f; } c; c.i = (unsigned)u << 16; return c.f;
}
__device__ __forceinline__ ushort_t f2bf(float f) {
  union { float f; unsigned u; } c; c.f = f;
  unsigned r = c.u + 0x7FFF + ((c.u >> 16) & 1);
  return (ushort_t)(r >> 16);
}

// ---------------- CSR build via bucket counting sort (no global atomics) ----

__global__ __launch_bounds__(256) void k_hist(const int* __restrict__ col,
                                              int* __restrict__ ghist,
                                              int e, int nbuck, int chunk) {
  __shared__ int h[MAXBUCK];
  for (int p = threadIdx.x; p < nbuck; p += 256) h[p] = 0;
  __syncthreads();
  int s = blockIdx.x * chunk;
  int t = min(s + chunk, e);
  for (int i = s + threadIdx.x; i < t; i += 256)
    atomicAdd(&h[col[i] >> BUCK_SHIFT], 1);
  __syncthreads();
  for (int p = threadIdx.x; p < nbuck; p += 256)
    ghist[p * NSB + blockIdx.x] = h[p];
}

__global__ __launch_bounds__(256) void k_s1(int* __restrict__ ghist,
                                            int* __restrict__ btotal, int nbuck) {
  __shared__ int sd[256];
  int p = blockIdx.x;
  int tid = threadIdx.x;
  int idx = p * NSB + tid;
  int v = ghist[idx];
  sd[tid] = v;
  __syncthreads();
  for (int off = 1; off < 256; off <<= 1) {
    int t = (tid >= off) ? sd[tid - off] : 0;
    __syncthreads();
    sd[tid] += t;
    __syncthreads();
  }
  ghist[idx] = sd[tid] - v;    // exclusive within bucket
  if (tid == 255) btotal[p] = sd[255];
}

__global__ __launch_bounds__(512) void k_s2(const int* __restrict__ btotal,
                                            int* __restrict__ bstart,
                                            int nbuck, int e,
                                            int* __restrict__ rowptr, int n) {
  __shared__ int sd[512];
  int tid = threadIdx.x;
  int v = (tid < nbuck) ? btotal[tid] : 0;
  sd[tid] = v;
  __syncthreads();
  for (int off = 1; off < 512; off <<= 1) {
    int t = (tid >= off) ? sd[tid - off] : 0;
    __syncthreads();
    sd[tid] += t;
    __syncthreads();
  }
  if (tid < nbuck) bstart[tid] = sd[tid] - v;
  if (tid == 0) { bstart[nbuck] = e; rowptr[n] = e; }
}

__global__ __launch_bounds__(256) void k_scatter(const int* __restrict__ row,
                                                 const int* __restrict__ col,
                                                 const int* __restrict__ ghist,
                                                 const int* __restrict__ bstart,
                                                 unsigned* __restrict__ bpack,
                                                 int e, int nbuck, int chunk) {
  __shared__ int cur[MAXBUCK];
  for (int p = threadIdx.x; p < nbuck; p += 256)
    cur[p] = bstart[p] + ghist[p * NSB + blockIdx.x];
  __syncthreads();
  int s = blockIdx.x * chunk;
  int t = min(s + chunk, e);
  for (int i = s + threadIdx.x; i < t; i += 256) {
    int c = col[i];
    int pos = atomicAdd(&cur[c >> BUCK_SHIFT], 1);
    bpack[pos] = ((unsigned)(c & 255) << 17) | (unsigned)row[i];
  }
}

__global__ __launch_bounds__(256) void k_bsort(const unsigned* __restrict__ bpack,
                                               const int* __restrict__ bstart,
                                               int* __restrict__ rowptr,
                                               float* __restrict__ dis,
                                               int* __restrict__ srcidx, int n) {
  __shared__ int cnt[4096];
  __shared__ int excl[4097];
  __shared__ int sd[256];
  __shared__ int sbs, sbe;
  int tid = threadIdx.x;
  int p = blockIdx.x;
  for (int q = tid; q < 4096; q += 256) cnt[q] = 0;
  if (tid == 0) { sbs = bstart[p]; sbe = bstart[p + 1]; }
  __syncthreads();
  int bs = sbs, be = sbe;
  for (int i = bs + tid; i < be; i += 256) {
    unsigned v = bpack[i];
    int key = (int)((v >> 17) << 4) | (int)((v & 0x1FFFFu) >> CHUNK_SHIFT);
    atomicAdd(&cnt[key], 1);
  }
  __syncthreads();
  int base = tid * 16;
  int c[16]; int s = 0;
#pragma unroll
  for (int q = 0; q < 16; q++) { c[q] = cnt[base + q]; s += c[q]; }
  sd[tid] = s;
  __syncthreads();
  for (int off = 1; off < 256; off <<= 1) {
    int t = (tid >= off) ? sd[tid - off] : 0;
    __syncthreads();
    sd[tid] += t;
    __syncthreads();
  }
  int run = sd[tid] - s;
  int st = run;
#pragma unroll
  for (int q = 0; q < 16; q++) { excl[base + q] = run; run += c[q]; }
  if (tid == 255) excl[4096] = sd[255];
  int node = (p << BUCK_SHIFT) + tid;
  if (node < n) {
    rowptr[node] = bs + st;
    dis[node] = rsqrtf((float)(s + 1));  // +1 self loop
  }
  __syncthreads();
  for (int i = bs + tid; i < be; i += 256) {
    unsigned v = bpack[i];
    int key = (int)((v >> 17) << 4) | (int)((v & 0x1FFFFu) >> CHUNK_SHIFT);
    int q = atomicAdd(&excl[key], 1);
    srcidx[bs + q] = (int)(v & 0x1FFFFu);
  }
}

// ------- weight pack: WB[n][k] = W[k][n] in bf16; also zero stats -------

__global__ void k_wpack(const float* __restrict__ W1, const float* __restrict__ W2,
                        ushort_t* __restrict__ WB1, ushort_t* __restrict__ WB2,
                        float* __restrict__ stats) {
  int idx = blockIdx.x * 256 + threadIdx.x;
  if (blockIdx.x == 0) stats[threadIdx.x] = 0.f;
  if (idx < 128 * 128) {
    int nn = idx >> 7, k = idx & 127;
    WB1[idx] = f2bf(W1[k * HID_C + nn]);
  }
  int idx2 = idx - 128 * 128;
  if (idx2 >= 0 && idx2 < 64 * 128) {
    int nn = idx2 >> 7, k = idx2 & 127;
    WB2[idx2] = f2bf(W2[k * OUT_C + nn]);
  }
}

// ------- GEMM1 (MFMA bf16): h1p = bf16(dis*(x@W1)) -------
// LDS-staged coalesced x loads + LDS-transposed coalesced u16x8 stores.

__global__ __launch_bounds__(256) void k_gemm1_mfma(const float* __restrict__ x,
                                                    const ushort_t* __restrict__ WB,
                                                    const float* __restrict__ dis,
                                                    ushort_t* __restrict__ h1, int n) {
  __shared__ float xs[64][132];
  int tid = threadIdx.x;
  int base = blockIdx.x * 64;
#pragma unroll
  for (int k = 0; k < 8; k++) {
    int idx = tid + k * 256;          // 0..2047
    int r = idx >> 5;                 // row 0..63
    int c4 = (idx & 31) << 2;         // float col, step 4
    int rowi = base + r;
    float4 v;
    if (rowi < n) v = *reinterpret_cast<const float4*>(&x[(size_t)rowi * IN_C + c4]);
    else { v.x = 0.f; v.y = 0.f; v.z = 0.f; v.w = 0.f; }
    *reinterpret_cast<float4*>(&xs[r][c4]) = v;
  }
  __syncthreads();
  int wave = tid >> 6;
  int lane = tid & 63;
  int m = lane & 15;
  int kg = lane >> 4;
  int rowbase = base + wave * 16;
  f32x4 acc[8] = {};
#pragma unroll
  for (int ks = 0; ks < 4; ks++) {
    const float* xr = &xs[wave * 16 + m][ks * 32 + kg * 8];
    float4 a0 = *reinterpret_cast<const float4*>(xr);
    float4 a1 = *reinterpret_cast<const float4*>(xr + 4);
    bf16x8 a;
    a[0] = (short)f2bf(a0.x); a[1] = (short)f2bf(a0.y);
    a[2] = (short)f2bf(a0.z); a[3] = (short)f2bf(a0.w);
    a[4] = (short)f2bf(a1.x); a[5] = (short)f2bf(a1.y);
    a[6] = (short)f2bf(a1.z); a[7] = (short)f2bf(a1.w);
#pragma unroll
    for (int nt = 0; nt < 8; nt++) {
      bf16x8 b = *reinterpret_cast<const bf16x8*>(WB + (nt * 16 + m) * 128 + ks * 32 + kg * 8);
      acc[nt] = __builtin_amdgcn_mfma_f32_16x16x32_bf16(a, b, acc[nt], 0, 0, 0);
    }
  }
  // ---- epilogue: transpose through LDS (reuse xs), coalesced 16B stores ----
  ushort_t* hs = reinterpret_cast<ushort_t*>(&xs[0][0]);  // [64][136] ushort
  float dr_[4];
#pragma unroll
  for (int r = 0; r < 4; r++) {
    int rowi = rowbase + kg * 4 + r;
    dr_[r] = dis[rowi < n ? rowi : (n - 1)];
  }
  __syncthreads();                     // all xs reads done before overwrite
#pragma unroll
  for (int nt = 0; nt < 8; nt++)
#pragma unroll
    for (int r = 0; r < 4; r++)
      hs[(size_t)(wave * 16 + kg * 4 + r) * 136 + nt * 16 + m] = f2bf(dr_[r] * acc[nt][r]);
  __syncthreads();
#pragma unroll
  for (int k = 0; k < 4; k++) {
    int idx = tid + k * 256;           // 0..1023
    int r = idx >> 4;                  // row 0..63
    int c8 = (idx & 15) * 8;           // col 0..120
    int rowi = base + r;
    if (rowi < n)
      *reinterpret_cast<u16x8*>(&h1[(size_t)rowi * HID_C + c8]) =
          *reinterpret_cast<const u16x8*>(&hs[(size_t)r * 136 + c8]);
  }
}

// ------- GEMM2 (MFMA bf16, BN+ReLU fused; LDS-transposed coalesced stores) -------

__global__ __launch_bounds__(256) void k_gemm2_mfma(const ushort_t* __restrict__ aggb,
                                                    const ushort_t* __restrict__ WB,
                                                    const float* __restrict__ stats,
                                                    const float* __restrict__ gamma,
                                                    const float* __restrict__ beta,
                                                    const float* __restrict__ dis,
                                                    ushort_t* __restrict__ h2, int n) {
  __shared__ float bnp_s[256];
  __shared__ ushort_t hs2[64][72];
  int tid = threadIdx.x;
  if (tid < 128) {
    float inv_n = 1.f / (float)n;
    float mean = stats[tid] * inv_n;
    float var = stats[128 + tid] * inv_n - mean * mean;
    float istd = rsqrtf(var + BN_EPS);
    float sc = gamma[tid] * istd;
    bnp_s[tid] = sc;
    bnp_s[128 + tid] = beta[tid] - mean * sc;
  }
  __syncthreads();
  int wave = tid >> 6;
  int lane = tid & 63;
  int m = lane & 15;
  int kg = lane >> 4;
  int rowbase = blockIdx.x * 64 + wave * 16;
  int rrow = rowbase + m; if (rrow >= n) rrow = n - 1;
  const ushort_t* arow = aggb + (size_t)rrow * HID_C + kg * 8;
  f32x4 acc[4] = {};
#pragma unroll
  for (int ks = 0; ks < 4; ks++) {
    int kbase = ks * 32 + kg * 8;
    u16x8 av = *reinterpret_cast<const u16x8*>(arow + ks * 32);
    float v[8];
#pragma unroll
    for (int q = 0; q < 8; q++)
      v[q] = bf2f(av[q]) * bnp_s[kbase + q] + bnp_s[128 + kbase + q];
    bf16x8 a;
#pragma unroll
    for (int q = 0; q < 8; q++) a[q] = (short)f2bf(v[q] > 0.f ? v[q] : 0.f);
#pragma unroll
    for (int nt = 0; nt < 4; nt++) {
      bf16x8 b = *reinterpret_cast<const bf16x8*>(WB + (nt * 16 + m) * 128 + ks * 32 + kg * 8);
      acc[nt] = __builtin_amdgcn_mfma_f32_16x16x32_bf16(a, b, acc[nt], 0, 0, 0);
    }
  }
  // ---- epilogue: transpose through LDS, coalesced 16B stores ----
  float dr_[4];
#pragma unroll
  for (int r = 0; r < 4; r++) {
    int rowi = rowbase + kg * 4 + r;
    dr_[r] = dis[rowi < n ? rowi : (n - 1)];
  }
#pragma unroll
  for (int nt = 0; nt < 4; nt++)
#pragma unroll
    for (int r = 0; r < 4; r++)
      hs2[wave * 16 + kg * 4 + r][nt * 16 + m] = f2bf(dr_[r] * acc[nt][r]);
  __syncthreads();
#pragma unroll
  for (int k = 0; k < 2; k++) {
    int idx = tid + k * 256;           // 0..511
    int r = idx >> 3;                  // row 0..63
    int c8 = (idx & 7) * 8;            // col 0..56
    int rowi = blockIdx.x * 64 + r;
    if (rowi < n)
      *reinterpret_cast<u16x8*>(&h2[(size_t)rowi * OUT_C + c8]) =
          *reinterpret_cast<const u16x8*>(&hs2[r][c8]);
  }
}

// ------- SpMM1: XCD-parity channel halves (g = blockIdx&1 -> 64ch, 128B rows) -------
// XCDs 0,2,4,6 gather channels 0..63; 1,3,5,7 gather 64..127 -> per-XCD
// compulsory fill halves. Measured R14: 58.2us, FETCH 163MB (vs 62us/187MB).

__global__ __launch_bounds__(256) void k_spmm1_bf(const ushort_t* __restrict__ h,
                                                  const float* __restrict__ dis,
                                                  const int* __restrict__ rowptr,
                                                  const int* __restrict__ srcidx,
                                                  const float* __restrict__ bias,
                                                  ushort_t* __restrict__ outp, int n) {
  constexpr int C = HID_C;         // table stride
  int tid = threadIdx.x;
  int g = blockIdx.x & 1;          // channel half (XCD parity)
  int lane = tid & 7;              // 8 lanes x 8ch = 64 channels
  int r = tid >> 3;                // 32 rows per block
  int i = (blockIdx.x >> 1) * 32 + r;
  if (i >= n) return;
  int c8 = g * 64 + lane * 8;
  const ushort_t* hb = h + c8;

  float acc[8];
  u16x8 hv = *reinterpret_cast<const u16x8*>(hb + (size_t)i * C);
#pragma unroll
  for (int q = 0; q < 8; q++) acc[q] = bf2f(hv[q]);   // self loop (premult)

  int s = rowptr[i], t = rowptr[i + 1];
  int p = s;
  for (; p + 16 <= t; p += 16) {
    int j[16]; u16x8 v[16];
#pragma unroll
    for (int k = 0; k < 16; k++) j[k] = srcidx[p + k];
#pragma unroll
    for (int k = 0; k < 16; k++)
      v[k] = *reinterpret_cast<const u16x8*>(hb + (size_t)j[k] * C);
#pragma unroll
    for (int k = 0; k < 16; k++)
#pragma unroll
      for (int q = 0; q < 8; q++) acc[q] += bf2f(v[k][q]);
  }
  for (; p + 4 <= t; p += 4) {
    int j[4]; u16x8 v[4];
#pragma unroll
    for (int k = 0; k < 4; k++) j[k] = srcidx[p + k];
#pragma unroll
    for (int k = 0; k < 4; k++)
      v[k] = *reinterpret_cast<const u16x8*>(hb + (size_t)j[k] * C);
#pragma unroll
    for (int k = 0; k < 4; k++)
#pragma unroll
      for (int q = 0; q < 8; q++) acc[q] += bf2f(v[k][q]);
  }
  for (; p < t; p++) {
    int j = srcidx[p];
    u16x8 v = *reinterpret_cast<const u16x8*>(hb + (size_t)j * C);
#pragma unroll
    for (int q = 0; q < 8; q++) acc[q] += bf2f(v[q]);
  }

  float di = dis[i];
  float4 b0 = *reinterpret_cast<const float4*>(bias + c8);
  float4 b1v = *reinterpret_cast<const float4*>(bias + c8 + 4);
  u16x8 o;
  o[0] = f2bf(di * acc[0] + b0.x);  o[1] = f2bf(di * acc[1] + b0.y);
  o[2] = f2bf(di * acc[2] + b0.z);  o[3] = f2bf(di * acc[3] + b0.w);
  o[4] = f2bf(di * acc[4] + b1v.x); o[5] = f2bf(di * acc[5] + b1v.y);
  o[6] = f2bf(di * acc[6] + b1v.z); o[7] = f2bf(di * acc[7] + b1v.w);
  *reinterpret_cast<u16x8*>(outp + (size_t)i * C + c8) = o;
}

// ------- SpMM2 (bf16 gather of premultiplied h2p, full 64ch) -> fp32 out -------
// (R13 known-good form; R14's 32ch halving regressed ~+21us -> reverted.)

__global__ __launch_bounds__(256) void k_spmm2_bf(const ushort_t* __restrict__ h,
                                                  const float* __restrict__ dis,
                                                  const int* __restrict__ rowptr,
                                                  const int* __restrict__ srcidx,
                                                  const float* __restrict__ bias,
                                                  float* __restrict__ outp, int n) {
  constexpr int C = OUT_C;
  constexpr int LPR = C / 8;       // 8
  constexpr int ROWS = 256 / LPR;  // 32
  int tid = threadIdx.x;
  int lane = tid & (LPR - 1);
  int r = tid / LPR;
  int i = blockIdx.x * ROWS + r;
  if (i >= n) return;
  int c8 = lane * 8;
  const ushort_t* hb = h + c8;

  float acc[8];
  u16x8 hv = *reinterpret_cast<const u16x8*>(hb + (size_t)i * C);
#pragma unroll
  for (int q = 0; q < 8; q++) acc[q] = bf2f(hv[q]);

  int s = rowptr[i], t = rowptr[i + 1];
  int p = s;
  for (; p + 16 <= t; p += 16) {
    int j[16]; u16x8 v[16];
#pragma unroll
    for (int k = 0; k < 16; k++) j[k] = srcidx[p + k];
#pragma unroll
    for (int k = 0; k < 16; k++)
      v[k] = *reinterpret_cast<const u16x8*>(hb + (size_t)j[k] * C);
#pragma unroll
    for (int k = 0; k < 16; k++)
#pragma unroll
      for (int q = 0; q < 8; q++) acc[q] += bf2f(v[k][q]);
  }
  for (; p + 4 <= t; p += 4) {
    int j[4]; u16x8 v[4];
#pragma unroll
    for (int k = 0; k < 4; k++) j[k] = srcidx[p + k];
#pragma unroll
    for (int k = 0; k < 4; k++)
      v[k] = *reinterpret_cast<const u16x8*>(hb + (size_t)j[k] * C);
#pragma unroll
    for (int k = 0; k < 4; k++)
#pragma unroll
      for (int q = 0; q < 8; q++) acc[q] += bf2f(v[k][q]);
  }
  for (; p < t; p++) {
    int j = srcidx[p];
    u16x8 v = *reinterpret_cast<const u16x8*>(hb + (size_t)j * C);
#pragma unroll
    for (int q = 0; q < 8; q++) acc[q] += bf2f(v[q]);
  }

  float di = dis[i];
  float4 b0 = *reinterpret_cast<const float4*>(bias + c8);
  float4 b1v = *reinterpret_cast<const float4*>(bias + c8 + 4);
  float4 o0, o1;
  o0.x = di * acc[0] + b0.x;  o0.y = di * acc[1] + b0.y;
  o0.z = di * acc[2] + b0.z;  o0.w = di * acc[3] + b0.w;
  o1.x = di * acc[4] + b1v.x; o1.y = di * acc[5] + b1v.y;
  o1.z = di * acc[6] + b1v.z; o1.w = di * acc[7] + b1v.w;
  float* op = outp + (size_t)i * C + c8;
  *reinterpret_cast<float4*>(op) = o0;
  *reinterpret_cast<float4*>(op + 4) = o1;
}

// ---------------- BN stats over bf16 agg (vectorized) ----------------

__global__ __launch_bounds__(256) void k_bnstats(const ushort_t* __restrict__ aggb,
                                                 float* __restrict__ stats, int n) {
  __shared__ float lsum[256 * 8];
  __shared__ float lsq[256 * 8];
  int tid = threadIdx.x;
  int lane = tid & 15;          // channel-octet
  int rg = tid >> 4;            // row-in-group 0..15
  float s[8] = {}, q[8] = {};
  for (int row = blockIdx.x * 16 + rg; row < n; row += gridDim.x * 16) {
    u16x8 v = *reinterpret_cast<const u16x8*>(aggb + (size_t)row * HID_C + lane * 8);
#pragma unroll
    for (int k = 0; k < 8; k++) {
      float f = bf2f(v[k]);
      s[k] += f;
      q[k] += f * f;
    }
  }
#pragma unroll
  for (int k = 0; k < 8; k++) { lsum[tid * 8 + k] = s[k]; lsq[tid * 8 + k] = q[k]; }
  __syncthreads();
  if (tid < 128) {
    int ln = tid >> 3, k = tid & 7;   // channel c = ln*8+k
    float ss = 0.f, qq = 0.f;
    for (int r = 0; r < 16; r++) {
      int idx = ((r << 4) + ln) * 8 + k;
      ss += lsum[idx];
      qq += lsq[idx];
    }
    atomicAdd(&stats[tid], ss);
    atomicAdd(&stats[128 + tid], qq);
  }
}

// ---------------- launch ----------------

extern "C" void kernel_launch(void* const* d_in, const int* in_sizes, int n_in,
                              void* d_out, int out_size, void* d_ws, size_t ws_size,
                              hipStream_t stream) {
  const float* x     = (const float*)d_in[0];
  const int*   edge  = (const int*)d_in[1];
  const float* W1    = (const float*)d_in[2];
  const float* b1    = (const float*)d_in[3];
  const float* gamma = (const float*)d_in[4];
  const float* beta  = (const float*)d_in[5];
  const float* W2    = (const float*)d_in[6];
  const float* b2    = (const float*)d_in[7];
  float* out = (float*)d_out;

  int n = in_sizes[0] / IN_C;
  int e = in_sizes[1] / 2;
  int n64 = ((n + 63) / 64) * 64;
  int nbuck = (n + (1 << BUCK_SHIFT) - 1) >> BUCK_SHIFT;
  const int* row = edge;      // edge_index[0] = source j
  const int* col = edge + e;  // edge_index[1] = target i

  char* ws = (char*)d_ws;
  size_t off = 0;
  auto alloc = [&](size_t bytes) {
    void* p = ws + off;
    off = (off + bytes + 255) & ~(size_t)255;
    return p;
  };
  // persistent
  float*    dis   = (float*)alloc((size_t)n * 4);
  int*      rowp  = (int*)alloc((size_t)(n + 1) * 4);
  int*      srci  = (int*)alloc((size_t)e * 4);
  ushort_t* WB1   = (ushort_t*)alloc(128 * 128 * 2);
  ushort_t* WB2   = (ushort_t*)alloc(64 * 128 * 2);
  ushort_t* h1b   = (ushort_t*)alloc((size_t)n64 * HID_C * 2);
  ushort_t* aggb  = (ushort_t*)alloc((size_t)n64 * HID_C * 2);
  ushort_t* h2b   = (ushort_t*)alloc((size_t)n64 * OUT_C * 2);
  float*    stats = (float*)alloc(256 * 4);
  // transients overlay aggb (dead until spmm1 writes it, after bsort)
  char* tr = (char*)aggb;
  unsigned* bpack = (unsigned*)tr;                       tr += (size_t)e * 4;
  int* ghist  = (int*)tr;                                tr += (size_t)NSB * nbuck * 4;
  int* btotal = (int*)tr;                                tr += (size_t)(nbuck + 1) * 4;
  int* bstart = (int*)tr;
  (void)ws_size; (void)n_in; (void)out_size;

  int chunk = (e + NSB - 1) / NSB;
  int nb64 = n64 / 64;
  int nb32 = (n + 31) / 32;

  k_wpack  <<<96, 256, 0, stream>>>(W1, W2, WB1, WB2, stats);
  k_hist   <<<NSB, 256, 0, stream>>>(col, ghist, e, nbuck, chunk);
  k_s1     <<<nbuck, 256, 0, stream>>>(ghist, btotal, nbuck);
  k_s2     <<<1, 512, 0, stream>>>(btotal, bstart, nbuck, e, rowp, n);
  k_scatter<<<NSB, 256, 0, stream>>>(row, col, ghist, bstart, bpack, e, nbuck, chunk);
  k_bsort  <<<nbuck, 256, 0, stream>>>(bpack, bstart, rowp, dis, srci, n);
  k_gemm1_mfma<<<nb64, 256, 0, stream>>>(x, WB1, dis, h1b, n);
  k_spmm1_bf<<<2 * nb32, 256, 0, stream>>>(h1b, dis, rowp, srci, b1, aggb, n);
  k_bnstats<<<512, 256, 0, stream>>>(aggb, stats, n);
  k_gemm2_mfma<<<nb64, 256, 0, stream>>>(aggb, WB2, stats, gamma, beta, dis, h2b, n);
  k_spmm2_bf<<<nb32, 256, 0, stream>>>(h2b, dis, rowp, srci, b2, out, n);
}